// Round 10
// baseline (566.548 us; speedup 1.0000x reference)
//
#include <hip/hip_runtime.h>

typedef float f4 __attribute__((ext_vector_type(4)));

#define NN 4096
#define DD 64
#define SS 4
#define COPY_OFF 67108864LL   // 4*4096*4096
#define OUT_TOTAL 134217728LL // 2*4*4096*4096
#define T_ELEMS 1048576       // 4*4096*64

// ---------------- Kernel 1: T[row][e] = sum_d x1[row][d] * W[d][e] ----------------
__global__ __launch_bounds__(256) void compute_T_kernel(
    const float* __restrict__ x1, const float* __restrict__ W, float* __restrict__ T)
{
    __shared__ float Ws[64 * 64];
    __shared__ float x1s[4 * 64];
    int t = threadIdx.x;
#pragma unroll
    for (int r = 0; r < 4; ++r) {
        int f = t + 256 * r;
        reinterpret_cast<f4*>(Ws)[f] = reinterpret_cast<const f4*>(W)[f];
    }
    long long rowbase = (long long)blockIdx.x * 4;
    if (t < 64)
        reinterpret_cast<f4*>(x1s)[t] =
            reinterpret_cast<const f4*>(x1 + rowbase * 64)[t];
    __syncthreads();
    int rr = t >> 6, e = t & 63;
    float acc = 0.f;
#pragma unroll
    for (int d = 0; d < 64; ++d)
        acc = fmaf(x1s[rr * 64 + d], Ws[d * 64 + e], acc);
    T[(rowbase + rr) * 64 + e] = acc;  // coalesced
}

// ---------------- Kernel 2: out[s,i,j] = sum_e T[s,i,e] * x0[s,j,e] + bias --------
// 64x64 tile / block, 256 threads, 32 KB LDS -> 5 blocks/CU (5 waves/SIMD).
// Goal: many independent block streams so 32 KB store bursts hide under other
// blocks' compute. Plain (cached) stores so L2 write-back smooths the bursts.
// LDS k-major [64][64], XOR swizzle pos = k*64 + (i ^ (k&28)):
//   staging scalar writes 2-way (free); A-reads broadcast x16 (free);
//   B-reads 16 contiguous b128 = 2 words/bank (free).
__global__ __launch_bounds__(256, 5) void bilin_gemm_kernel(
    const float* __restrict__ T, const float* __restrict__ x0,
    const float* __restrict__ bias_p, float* __restrict__ out, int skip_tail)
{
    __shared__ float As[64 * 64];
    __shared__ float Bs[64 * 64];
    int t = threadIdx.x;
    int bid = blockIdx.x;
    int jt = bid & 63, it = (bid >> 6) & 63, s = bid >> 12;
    int i0 = it * 64, j0 = jt * 64;
    const float* Ta = T  + ((long long)(s * NN + i0) << 6);
    const float* Xa = x0 + ((long long)(s * NN + j0) << 6);

    // Stage both 16 KB tiles: 1024 f4 each, 256 threads -> 4 f4/thread/tile.
#pragma unroll
    for (int r = 0; r < 4; ++r) {
        int f = t + 256 * r;       // 0..1023
        int ii = f >> 4;           // row within tile (0..63)
        int k0 = (f & 15) << 2;    // k base (0..60)
        f4 va = *reinterpret_cast<const f4*>(Ta + ii * 64 + k0);
        f4 vb = *reinterpret_cast<const f4*>(Xa + ii * 64 + k0);
#pragma unroll
        for (int q = 0; q < 4; ++q) {
            int k = k0 + q;
            int pos = (k << 6) + (ii ^ (k & 28));
            As[pos] = va[q];
            Bs[pos] = vb[q];
        }
    }
    __syncthreads();

    int tx = t & 15, ty = t >> 4;   // ty in [0,16)
    float bias = bias_p[0];
    float acc[4][4];
#pragma unroll
    for (int m = 0; m < 4; ++m)
#pragma unroll
        for (int n = 0; n < 4; ++n) acc[m][n] = bias;  // fold bias into init

#pragma unroll 8
    for (int k = 0; k < 64; ++k) {
        int swz = k & 28;
        int kb = k << 6;
        f4 a = *reinterpret_cast<const f4*>(&As[kb + ((ty * 4) ^ swz)]);
        f4 b = *reinterpret_cast<const f4*>(&Bs[kb + ((tx * 4) ^ swz)]);
#pragma unroll
        for (int m = 0; m < 4; ++m)
#pragma unroll
            for (int n = 0; n < 4; ++n)
                acc[m][n] = fmaf(a[m], b[n], acc[m][n]);
    }

    bool skip = skip_tail && (s == 3) && (i0 >= 3840);
#pragma unroll
    for (int m = 0; m < 4; ++m) {
        int row = i0 + ty * 4 + m;
        long long o0 = ((long long)(s * NN + row) << 12) + j0 + tx * 4;
        f4 c;
        c[0] = acc[m][0]; c[1] = acc[m][1]; c[2] = acc[m][2]; c[3] = acc[m][3];
        *reinterpret_cast<f4*>(out + o0) = c;
        if (!skip)
            *reinterpret_cast<f4*>(out + o0 + COPY_OFF) = c;
    }
}

// Fallback fixup: copy the T-scratch region (copy-1, s=3, rows 3840..4095)
// from the identical copy-0 region.
__global__ __launch_bounds__(256) void fixup_kernel(float* __restrict__ out)
{
    int idx = blockIdx.x * 256 + threadIdx.x;  // 262144 float4s
    const f4* src = reinterpret_cast<const f4*>(out + 66060288LL); // copy0 s=3 row 3840
    f4* dst = reinterpret_cast<f4*>(out + (OUT_TOTAL - T_ELEMS));
    dst[idx] = src[idx];
}

extern "C" void kernel_launch(void* const* d_in, const int* in_sizes, int n_in,
                              void* d_out, int out_size, void* d_ws, size_t ws_size,
                              hipStream_t stream)
{
    const float* x0   = (const float*)d_in[0];  // tensor0 (S,N,D)
    const float* x1   = (const float*)d_in[1];  // tensor1 (S,N,D)
    const float* W    = (const float*)d_in[2];  // kernel (D,D)
    const float* bias = (const float*)d_in[3];  // scalar

    float* out = (float*)d_out;
    bool use_ws = ws_size >= (size_t)T_ELEMS * sizeof(float);
    float* T = use_ws ? (float*)d_ws : out + (OUT_TOTAL - T_ELEMS);

    compute_T_kernel<<<4096, 256, 0, stream>>>(x1, W, T);
    bilin_gemm_kernel<<<16384, 256, 0, stream>>>(T, x0, bias, out, use_ws ? 0 : 1);
    if (!use_ws)
        fixup_kernel<<<1024, 256, 0, stream>>>(out);
}